// Round 1
// baseline (173.375 us; speedup 1.0000x reference)
//
#include <hip/hip_runtime.h>

// Involution: B=4, C=256, H=W=56, K=7, GC=16 -> G=16, Cr=64, K2=49, OCH=784
// ws layout: mid [4][64][3136] fp32 (3.21 MB) | w2 [4][784][3136] fp32 (39.3 MB)

#define EPS 1e-5f

// ---------------- Kernel 1: conv1 (1x1, 256->64) + BN + ReLU ----------------
// GEMM: mid[b][o][p] = relu(bn(sum_c w1[o][c] * x[b][c][p]))
// block: 256 thr, tile = 64 o x 64 px, K staged in 4 chunks of 64.
__global__ __launch_bounds__(256) void k1_conv1(
    const float* __restrict__ x, const float* __restrict__ w1,
    const float* __restrict__ gamma, const float* __restrict__ beta,
    const float* __restrict__ mean, const float* __restrict__ var,
    float* __restrict__ mid)
{
    __shared__ float lx[64 * 64];   // [cchunk][px]
    __shared__ float lw[64 * 64];   // [o][cchunk]
    const int t  = threadIdx.x;
    const int b  = blockIdx.y;
    const int p0 = blockIdx.x * 64;
    const int pxA = t & 31, pxB = pxA + 32;
    const int ob  = (t >> 5) * 8;          // 8 outputs per thread
    float acc[8][2];
#pragma unroll
    for (int i = 0; i < 8; ++i) { acc[i][0] = 0.f; acc[i][1] = 0.f; }

    for (int c0 = 0; c0 < 256; c0 += 64) {
#pragma unroll
        for (int i = 0; i < 16; ++i) {
            int idx = t + i * 256;
            int cc = idx >> 6, px = idx & 63;
            lx[idx] = x[(b * 256 + c0 + cc) * 3136 + p0 + px];
            int o = idx >> 6, cw = idx & 63;
            lw[idx] = w1[o * 256 + c0 + cw];
        }
        __syncthreads();
        for (int cc = 0; cc < 64; ++cc) {
            float xa = lx[cc * 64 + pxA];
            float xb = lx[cc * 64 + pxB];
#pragma unroll
            for (int i = 0; i < 8; ++i) {
                float wv = lw[(ob + i) * 64 + cc];
                acc[i][0] = fmaf(wv, xa, acc[i][0]);
                acc[i][1] = fmaf(wv, xb, acc[i][1]);
            }
        }
        __syncthreads();
    }
#pragma unroll
    for (int i = 0; i < 8; ++i) {
        int o = ob + i;
        float s   = gamma[o] * rsqrtf(var[o] + EPS);
        float off = beta[o] - mean[o] * s;
        float va = fmaxf(fmaf(acc[i][0], s, off), 0.f);
        float vb = fmaxf(fmaf(acc[i][1], s, off), 0.f);
        mid[(b * 64 + o) * 3136 + p0 + pxA] = va;
        mid[(b * 64 + o) * 3136 + p0 + pxB] = vb;
    }
}

// ---------------- Kernel 2: conv2 (1x1, 64->784) -----------------------------
// GEMM: w2[b][o][p] = bias[o] + sum_c cw[o][c] * mid[b][c][p]
// block: 256 thr, tile = 112 o x 112 px, K=64 single stage, 7x7 register tile.
__global__ __launch_bounds__(256) void k2_conv2(
    const float* __restrict__ mid, const float* __restrict__ cw,
    const float* __restrict__ cb, float* __restrict__ w2)
{
    __shared__ float lm[64 * 112];   // [c][px]
    __shared__ float lw[112 * 65];   // [o][c], padded +1 to dodge bank stride
    const int t  = threadIdx.x;
    const int b  = blockIdx.z;
    const int o0 = blockIdx.y * 112;
    const int p0 = blockIdx.x * 112;

    for (int idx = t; idx < 64 * 112; idx += 256) {
        int cc = idx / 112, px = idx % 112;
        lm[idx] = mid[(b * 64 + cc) * 3136 + p0 + px];
    }
    for (int idx = t; idx < 112 * 64; idx += 256) {
        int o = idx >> 6, cc = idx & 63;
        lw[o * 65 + cc] = cw[(o0 + o) * 64 + cc];
    }
    __syncthreads();

    const int ty = t >> 4, tx = t & 15;
    const int ob = ty * 7, pb = tx * 7;
    float acc[7][7];
#pragma unroll
    for (int i = 0; i < 7; ++i)
#pragma unroll
        for (int j = 0; j < 7; ++j) acc[i][j] = 0.f;

    for (int cc = 0; cc < 64; ++cc) {
        float mv[7], wv[7];
#pragma unroll
        for (int j = 0; j < 7; ++j) mv[j] = lm[cc * 112 + pb + j];
#pragma unroll
        for (int i = 0; i < 7; ++i) wv[i] = lw[(ob + i) * 65 + cc];
#pragma unroll
        for (int i = 0; i < 7; ++i)
#pragma unroll
            for (int j = 0; j < 7; ++j)
                acc[i][j] = fmaf(wv[i], mv[j], acc[i][j]);
    }
#pragma unroll
    for (int i = 0; i < 7; ++i) {
        float bias = cb[o0 + ob + i];
#pragma unroll
        for (int j = 0; j < 7; ++j)
            w2[(size_t)(b * 784 + o0 + ob + i) * 3136 + p0 + pb + j] = acc[i][j] + bias;
    }
}

// ---------------- Kernel 3: unfold + weighted reduce -------------------------
// out[b][g*16+cc][h][w] = sum_k w2[b][g*49+k][h][w] * xpad[b][g*16+cc][h+kh-3][w+kw-3]
// block: (b, g, 8x8 spatial tile). x halo + w2 tile in LDS; sliding-row regs.
__global__ __launch_bounds__(256) void k3_apply(
    const float* __restrict__ x, const float* __restrict__ w2,
    float* __restrict__ out)
{
    __shared__ __align__(16) float lx[16 * 196];  // [cc][14 rows][14 cols]
    __shared__ __align__(16) float lw[49 * 64];   // [k][px], px = sh*8+sw
    const int t = threadIdx.x;
    const int b = blockIdx.z, g = blockIdx.y;
    const int th = blockIdx.x / 7, tw = blockIdx.x % 7;
    const int h0 = th * 8, w0 = tw * 8;

    for (int idx = t; idx < 16 * 196; idx += 256) {
        int cc = idx / 196, r = idx % 196;
        int rr = r / 14, col = r % 14;
        int gh = h0 + rr - 3, gw = w0 + col - 3;
        float v = 0.f;
        if (gh >= 0 && gh < 56 && gw >= 0 && gw < 56)
            v = x[(b * 256 + g * 16 + cc) * 3136 + gh * 56 + gw];
        lx[idx] = v;
    }
    for (int idx = t; idx < 49 * 64; idx += 256) {
        int k = idx >> 6, px = idx & 63;
        int sh = px >> 3, sw = px & 7;
        lw[idx] = w2[(size_t)(b * 784 + g * 49 + k) * 3136 + (h0 + sh) * 56 + w0 + sw];
    }
    __syncthreads();

    const int cc = t >> 4, pxg = t & 15;
    const int sh = pxg >> 1, sw4 = (pxg & 1) * 4;   // 4 consecutive out pixels
    float a0 = 0.f, a1 = 0.f, a2 = 0.f, a3 = 0.f;
#pragma unroll
    for (int kh = 0; kh < 7; ++kh) {
        float xr[10];
#pragma unroll
        for (int j = 0; j < 10; ++j)
            xr[j] = lx[cc * 196 + (sh + kh) * 14 + sw4 + j];
#pragma unroll
        for (int kw = 0; kw < 7; ++kw) {
            int k = kh * 7 + kw;
            const float4 wv = *(const float4*)&lw[k * 64 + pxg * 4];
            a0 = fmaf(wv.x, xr[kw + 0], a0);
            a1 = fmaf(wv.y, xr[kw + 1], a1);
            a2 = fmaf(wv.z, xr[kw + 2], a2);
            a3 = fmaf(wv.w, xr[kw + 3], a3);
        }
    }
    float4 o4 = make_float4(a0, a1, a2, a3);
    *(float4*)&out[(b * 256 + g * 16 + cc) * 3136 + (h0 + sh) * 56 + w0 + sw4] = o4;
}

extern "C" void kernel_launch(void* const* d_in, const int* in_sizes, int n_in,
                              void* d_out, int out_size, void* d_ws, size_t ws_size,
                              hipStream_t stream) {
    const float* x     = (const float*)d_in[0];
    const float* w1    = (const float*)d_in[1];
    const float* gamma = (const float*)d_in[2];
    const float* beta  = (const float*)d_in[3];
    const float* mean  = (const float*)d_in[4];
    const float* var   = (const float*)d_in[5];
    const float* cw    = (const float*)d_in[6];
    const float* cb    = (const float*)d_in[7];
    float* out = (float*)d_out;

    float* mid = (float*)d_ws;                       // 4*64*3136   = 802816 f
    float* w2  = mid + 4 * 64 * 3136;                // 4*784*3136  = 9834496 f

    k1_conv1<<<dim3(49, 4), 256, 0, stream>>>(x, w1, gamma, beta, mean, var, mid);
    k2_conv2<<<dim3(28, 7, 4), 256, 0, stream>>>(mid, cw, cb, w2);
    k3_apply<<<dim3(49, 16, 4), 256, 0, stream>>>(x, w2, out);
}